// Round 8
// baseline (760.665 us; speedup 1.0000x reference)
//
#include <hip/hip_runtime.h>
#include <math.h>

// Problem constants
#define D_FEAT   128
#define O_SIZE   256
#define N_NEUR   1024
#define STEPS_PER_WG 8
#define N_CHAIN_WG   (O_SIZE / STEPS_PER_WG)     // 32 chain blocks
#define N_WRITER_WG  (256 - N_CHAIN_WG)          // 224 out-writer blocks
#define N_BLOCKS     256                          // 1 block/CU, all resident
#define N_ITEMS      (O_SIZE * 8)                 // out work items: (t, 128-row chunk)

typedef unsigned long long ull;
typedef float floatx4 __attribute__((ext_vector_type(4)));

// Module-owned channels (persist across graph replays; generation-tagged so no
// init/invalidate pass is needed).
__device__ ull      g_chan[N_CHAIN_WG][D_FEAT];  // baton: (tag<<32)|bits(v_j), tag=(gen<<8)|g
__device__ ull      g_uchan[O_SIZE][D_FEAT];     // u:     (tag<<32)|bits(u_j), tag=(gen<<8)|t
__device__ unsigned g_uflag[O_SIZE];             // per-step ready flag = (gen<<8)|t
__device__ unsigned g_gen  = 1u;                 // generation; bumped by last block each launch
__device__ int      g_done = 0;                  // completion counter (reset each launch)

// Fast, safe tanh: |err| ~1e-7, no inf/nan for any input.
__device__ __forceinline__ float tanh_fast(float x) {
    x = fminf(fmaxf(x, -20.f), 20.f);
    float e = __expf(2.f * x);
    return (e - 1.f) * __builtin_amdgcn_rcpf(e + 1.f);
}

// ---------------------------------------------------------------------------
// Single fused persistent kernel. Round-8: EXACT round-3 step body (150 µs
// reference — every step-body variant regressed: shfl 163, trees 163, explicit
// reg-dbuf 553 [scratch spill from opaque pins]) with ONE structural change:
// STEPS_PER_WG 4 -> 8. Hop = 4x0.39 compute + ~0.8 µs baton transit; transit
// is pure per-hop overhead, so halving hop count (64->32) saves ~25 µs.
//   bid <  32 : chain role; bid >= 32 : writer role (streams out[t] while the
//   chain runs). u crosses XCDs via agent-scope atomics (LLC).
// ---------------------------------------------------------------------------
__global__ __launch_bounds__(1024) void fused_kernel(
    const float* __restrict__ x,
    const float* __restrict__ pos_head,
    const float* __restrict__ pos_tail,
    const float* __restrict__ W,
    const float* __restrict__ a,
    float* __restrict__ out)
{
    const int bid = blockIdx.x;
    const int tid = threadIdx.x;
    const unsigned gen = g_gen;   // stable for this launch: bumped only after all
                                  // 256 blocks have passed the end-of-kernel counter

    if (bid < N_CHAIN_WG) {
        // ------------------------- chain role ------------------------------
        __shared__ __align__(16) float v_lds[D_FEAT];
        __shared__ float psum[8][D_FEAT];
        __shared__ float ptps[8][64];
        __shared__ float red[64];

        // XCD-local chain order: 4 consecutive g per XCD (32 WGs / 8 XCDs).
        const int g  = ((bid & 7) << 2) | (bid >> 3);
        const int s  = tid >> 7;      // m-block (16 rows)
        const int j  = tid & 127;     // column
        const int t0 = g * STEPS_PER_WG;

        // W[t0+k][s*16+m][j] -> w[k][m]  (128 values/thread, 512 KB/WG),
        // coalesced: consecutive tid = consecutive j. (Touch pattern: the
        // compiler discards and re-fetches in-step from L2 — empirically the
        // fastest arrangement; r7's "hold in registers" attempt spilled.)
        float w[STEPS_PER_WG][16];
        #pragma unroll
        for (int k = 0; k < STEPS_PER_WG; ++k) {
            #pragma unroll
            for (int m = 0; m < 16; ++m)
                w[k][m] = W[((size_t)(t0 + k) * D_FEAT + (s * 16 + m)) * D_FEAT + j];
        }
        float ascal[STEPS_PER_WG];
        #pragma unroll
        for (int k = 0; k < STEPS_PER_WG; ++k)
            ascal[k] = a[(t0 + k) * N_NEUR + (t0 + k) + 1];

        if (g == 0) {
            // v0 = (sum_k scores[k,0]) * colsum(x) — runs while W loads fly.
            {
                float acc = 0.f;
                #pragma unroll 8
                for (int ii = 0; ii < 32; ++ii)
                    acc += x[(s * 32 + ii) * D_FEAT + j];
                psum[s][j] = acc;
            }
            if (tid < 512) {
                const int kb = tid >> 6, d = tid & 63;
                float acc = 0.f;
                #pragma unroll 8
                for (int kk = 0; kk < 32; ++kk)
                    acc += pos_tail[(kb * 32 + kk) * 64 + d];
                ptps[kb][d] = acc;
            }
            __syncthreads();
            if (tid < 64) {
                float ptd = 0.f;
                #pragma unroll
                for (int kb = 0; kb < 8; ++kb) ptd += ptps[kb][tid];
                red[tid] = ptd * pos_head[tid];   // pos_head row 0
            }
            __syncthreads();
            if (tid < 128) {
                float sx = 0.f;
                #pragma unroll
                for (int s8 = 0; s8 < 8; ++s8) sx += psum[s8][tid];
                float ss0 = 0.f;
                #pragma unroll
                for (int d = 0; d < 64; ++d) ss0 += red[d];
                v_lds[tid] = ss0 * sx;            // v0
            }
        }

        // Force ALL W/a loads complete BEFORE the poll loop, so the 512 KB/WG
        // prefetch happens in parallel across all WGs at kernel start.
        float dummy = 0.f;
        #pragma unroll
        for (int k = 0; k < STEPS_PER_WG; ++k) {
            #pragma unroll
            for (int m = 0; m < 16; ++m) {
                asm volatile("" : "+v"(w[k][m]));
                dummy += w[k][m];
            }
            asm volatile("" : "+v"(ascal[k]));
        }
        asm volatile("" :: "v"(dummy));   // loads done HERE

        // Wait for the baton (v vector for step t0). g==0 already has v0.
        if (g > 0 && tid < 128) {
            const unsigned want = (gen << 8) | (unsigned)g;
            ull pk;
            for (;;) {
                pk = __hip_atomic_load(&g_chan[g][tid], __ATOMIC_RELAXED,
                                       __HIP_MEMORY_SCOPE_AGENT);
                if ((unsigned)(pk >> 32) == want) break;
                __builtin_amdgcn_s_sleep(1);
            }
            v_lds[tid] = __uint_as_float((unsigned)pk);
        }
        __syncthreads();   // v_lds ready; also separates g0's psum reuse

        // ---- steps loop: LDS-only body, NO global stores (critical path) ----
        float ureg[STEPS_PER_WG];   // u[t0+k][j], live in tid<128 only
        #pragma unroll
        for (int k = 0; k < STEPS_PER_WG; ++k) {
            float acc = 0.f;
            #pragma unroll
            for (int m = 0; m < 16; ++m)
                acc += v_lds[s * 16 + m] * w[k][m];   // LDS broadcast reads
            psum[s][j] = acc;
            __syncthreads();

            if (tid < 128) {
                float u = 0.f;
                #pragma unroll
                for (int ss = 0; ss < 8; ++ss) u += psum[ss][j];
                ureg[k] = u;
                const float vn = tanh_fast(ascal[k] * u);
                if (k < STEPS_PER_WG - 1) {
                    v_lds[j] = vn;
                } else if (g + 1 < N_CHAIN_WG) {
                    // Baton leaves HERE — everything after is shadow time.
                    const ull pk = (((ull)((gen << 8) | (unsigned)(g + 1))) << 32) |
                                   (ull)__float_as_uint(vn);
                    __hip_atomic_store(&g_chan[g + 1][j], pk, __ATOMIC_RELAXED,
                                       __HIP_MEMORY_SCOPE_AGENT);
                }
            }
            __syncthreads();   // protects psum reuse + v_lds update
        }

        // ---- post-baton publication (overlapped with next chain WG) ----
        if (tid < 128) {
            #pragma unroll
            for (int k = 0; k < STEPS_PER_WG; ++k) {
                const int t = t0 + k;
                const ull upk = (((ull)((gen << 8) | (unsigned)t)) << 32) |
                                (ull)__float_as_uint(ureg[k]);
                __hip_atomic_store(&g_uchan[t][j], upk, __ATOMIC_RELAXED,
                                   __HIP_MEMORY_SCOPE_AGENT);
            }
        }
        __syncthreads();   // every wave's uchan stores ACKed at LLC past here
        if (tid < STEPS_PER_WG) {
            const int t = t0 + tid;
            __hip_atomic_store(&g_uflag[t], (gen << 8) | (unsigned)t,
                               __ATOMIC_RELAXED, __HIP_MEMORY_SCOPE_AGENT);
        }
    } else {
        // ------------------------- writer role -----------------------------
        // Item i -> (t = i>>3, c = i&7): 128 output rows, 64 KB each.
        const int wid = bid - N_CHAIN_WG;
        const int j4  = tid & 31;                 // float4 column
        for (int i = wid; i < N_ITEMS; i += N_WRITER_WG) {
            const int t = i >> 3;
            const int c = i & 7;
            const unsigned want = (gen << 8) | (unsigned)t;
            if (tid == 0) {   // single poller per WG: LLC poll traffic ~KB/µs
                while (__hip_atomic_load(&g_uflag[t], __ATOMIC_RELAXED,
                                         __HIP_MEMORY_SCOPE_AGENT) != want)
                    __builtin_amdgcn_s_sleep(8);
            }
            __syncthreads();

            // One-shot u read from LLC (agent atomics — never the local L2).
            const ull e0 = __hip_atomic_load(&g_uchan[t][4 * j4 + 0], __ATOMIC_RELAXED, __HIP_MEMORY_SCOPE_AGENT);
            const ull e1 = __hip_atomic_load(&g_uchan[t][4 * j4 + 1], __ATOMIC_RELAXED, __HIP_MEMORY_SCOPE_AGENT);
            const ull e2 = __hip_atomic_load(&g_uchan[t][4 * j4 + 2], __ATOMIC_RELAXED, __HIP_MEMORY_SCOPE_AGENT);
            const ull e3 = __hip_atomic_load(&g_uchan[t][4 * j4 + 3], __ATOMIC_RELAXED, __HIP_MEMORY_SCOPE_AGENT);
            const float u0 = __uint_as_float((unsigned)e0);
            const float u1 = __uint_as_float((unsigned)e1);
            const float u2 = __uint_as_float((unsigned)e2);
            const float u3 = __uint_as_float((unsigned)e3);

            const int lbase = (c << 7) + (tid >> 5);
            #pragma unroll
            for (int p = 0; p < 4; ++p) {
                const int row = (t << 10) + lbase + (p << 5);   // t*1024 + l
                const float sc = a[row];
                floatx4 r;
                r.x = tanh_fast(sc * u0);
                r.y = tanh_fast(sc * u1);
                r.z = tanh_fast(sc * u2);
                r.w = tanh_fast(sc * u3);
                __builtin_nontemporal_store(r, (floatx4*)out + (((size_t)row) << 5) + j4);
            }
        }
    }

    // Generation bump: the 256th block to finish resets g_done and advances
    // g_gen. Every block read g_gen at entry (all resident from t=0), so no
    // block can observe the bump within this launch; the next launch (stream-
    // ordered) sees it via the kernel-boundary flush.
    __syncthreads();
    if (tid == 0) {
        const int old = atomicAdd(&g_done, 1);
        if (old == N_BLOCKS - 1) {
            __hip_atomic_store(&g_done, 0, __ATOMIC_RELAXED, __HIP_MEMORY_SCOPE_AGENT);
            __hip_atomic_store(&g_gen, gen + 1u, __ATOMIC_RELAXED, __HIP_MEMORY_SCOPE_AGENT);
        }
    }
}

// ---------------------------------------------------------------------------
extern "C" void kernel_launch(void* const* d_in, const int* in_sizes, int n_in,
                              void* d_out, int out_size, void* d_ws, size_t ws_size,
                              hipStream_t stream)
{
    const float* x        = (const float*)d_in[0];
    const float* pos_head = (const float*)d_in[1];
    const float* pos_tail = (const float*)d_in[2];
    const float* W        = (const float*)d_in[3];
    const float* a        = (const float*)d_in[4];
    float*       out      = (float*)d_out;

    hipLaunchKernelGGL(fused_kernel, dim3(N_BLOCKS), dim3(1024), 0, stream,
                       x, pos_head, pos_tail, W, a, out);
}

// Round 9
// 291.441 us; speedup vs baseline: 2.6100x; 2.6100x over previous
//
#include <hip/hip_runtime.h>
#include <math.h>

// Problem constants
#define D_FEAT   128
#define O_SIZE   256
#define N_NEUR   1024
#define STEPS_PER_WG 4
#define N_CHAIN_WG   (O_SIZE / STEPS_PER_WG)     // 64 chain blocks
#define N_WRITER_WG  192                          // out-writer blocks
#define N_BLOCKS     (N_CHAIN_WG + N_WRITER_WG)  // 256 = 1 block/CU, all resident
#define N_ITEMS      (O_SIZE * 8)                 // out work items: (t, 128-row chunk)

typedef unsigned long long ull;
typedef float floatx4 __attribute__((ext_vector_type(4)));

// Module-owned channels (persist across graph replays; generation-tagged so no
// init/invalidate pass is needed).
__device__ ull      g_chan[N_CHAIN_WG][D_FEAT];  // baton: (tag<<32)|bits(v_j), tag=(gen<<8)|g
__device__ ull      g_uchan[O_SIZE][D_FEAT];     // u:     (tag<<32)|bits(u_j), tag=(gen<<8)|t
__device__ unsigned g_uflag[O_SIZE];             // per-step ready flag = (gen<<8)|t
__device__ unsigned g_gen  = 1u;                 // generation; bumped by last block each launch
__device__ int      g_done = 0;                  // completion counter (reset each launch)

// Fast, safe tanh: |err| ~1e-7, no inf/nan for any input.
__device__ __forceinline__ float tanh_fast(float x) {
    x = fminf(fmaxf(x, -20.f), 20.f);
    float e = __expf(2.f * x);
    return (e - 1.f) * __builtin_amdgcn_rcpf(e + 1.f);
}

// ---------------------------------------------------------------------------
// Single fused persistent kernel — EXACT round-3 artifact (150 µs dispatch,
// best of 9 rounds). Probes that regressed and are permanently closed:
//   shfl single-barrier step (163), vec-read+FMA-tree step (163),
//   progress-gated polling (225), explicit W reg-double-buffer (553, spill),
//   STEPS_PER_WG=8 (626, spill — touch array past allocator limit goes to
//   scratch: WRITE_SIZE +10 MB of spill traffic).
// Structure:
//   bid <  64 : chain role. W touch-prefetch (L2 warm, compiler refetches
//               in-step — empirically optimal); per-step: LDS-only 2-barrier
//               body; u kept in regs; baton send at step 3; u-publication
//               and flags strictly post-baton (shadow time).
//   bid >= 64 : writer role: polls per-step flags, streams out[t]=tanh(a⊗u)
//               overlapped with the chain.
// u and batons cross XCDs via agent-scope atomics (LLC).
// ---------------------------------------------------------------------------
__global__ __launch_bounds__(1024) void fused_kernel(
    const float* __restrict__ x,
    const float* __restrict__ pos_head,
    const float* __restrict__ pos_tail,
    const float* __restrict__ W,
    const float* __restrict__ a,
    float* __restrict__ out)
{
    const int bid = blockIdx.x;
    const int tid = threadIdx.x;
    const unsigned gen = g_gen;   // stable for this launch: bumped only after all
                                  // 256 blocks have passed the end-of-kernel counter

    if (bid < N_CHAIN_WG) {
        // ------------------------- chain role ------------------------------
        __shared__ __align__(16) float v_lds[D_FEAT];
        __shared__ float psum[8][D_FEAT];
        __shared__ float ptps[8][64];
        __shared__ float red[64];

        const int g  = ((bid & 7) << 3) | (bid >> 3);   // XCD-local chain order
        const int s  = tid >> 7;      // m-block (16 rows)
        const int j  = tid & 127;     // column
        const int t0 = g * STEPS_PER_WG;

        // W[t0+k][s*16+m][j] -> w[k][m]  (64 values/thread, 256 KB/WG),
        // coalesced: consecutive tid = consecutive j.
        float w[STEPS_PER_WG][16];
        #pragma unroll
        for (int k = 0; k < STEPS_PER_WG; ++k) {
            #pragma unroll
            for (int m = 0; m < 16; ++m)
                w[k][m] = W[((size_t)(t0 + k) * D_FEAT + (s * 16 + m)) * D_FEAT + j];
        }
        float ascal[STEPS_PER_WG];
        #pragma unroll
        for (int k = 0; k < STEPS_PER_WG; ++k)
            ascal[k] = a[(t0 + k) * N_NEUR + (t0 + k) + 1];

        if (g == 0) {
            // v0 = (sum_k scores[k,0]) * colsum(x) — runs while W loads fly.
            {
                float acc = 0.f;
                #pragma unroll 8
                for (int ii = 0; ii < 32; ++ii)
                    acc += x[(s * 32 + ii) * D_FEAT + j];
                psum[s][j] = acc;
            }
            if (tid < 512) {
                const int kb = tid >> 6, d = tid & 63;
                float acc = 0.f;
                #pragma unroll 8
                for (int kk = 0; kk < 32; ++kk)
                    acc += pos_tail[(kb * 32 + kk) * 64 + d];
                ptps[kb][d] = acc;
            }
            __syncthreads();
            if (tid < 64) {
                float ptd = 0.f;
                #pragma unroll
                for (int kb = 0; kb < 8; ++kb) ptd += ptps[kb][tid];
                red[tid] = ptd * pos_head[tid];   // pos_head row 0
            }
            __syncthreads();
            if (tid < 128) {
                float sx = 0.f;
                #pragma unroll
                for (int s8 = 0; s8 < 8; ++s8) sx += psum[s8][tid];
                float ss0 = 0.f;
                #pragma unroll
                for (int d = 0; d < 64; ++d) ss0 += red[d];
                v_lds[tid] = ss0 * sx;            // v0
            }
        }

        // Force ALL W/a loads complete BEFORE the poll loop, so the 256 KB/WG
        // prefetch happens in parallel across all WGs at kernel start.
        float dummy = 0.f;
        #pragma unroll
        for (int k = 0; k < STEPS_PER_WG; ++k) {
            #pragma unroll
            for (int m = 0; m < 16; ++m) {
                asm volatile("" : "+v"(w[k][m]));
                dummy += w[k][m];
            }
            asm volatile("" : "+v"(ascal[k]));
        }
        asm volatile("" :: "v"(dummy));   // loads done HERE

        // Wait for the baton (v vector for step t0). g==0 already has v0.
        if (g > 0 && tid < 128) {
            const unsigned want = (gen << 8) | (unsigned)g;
            ull pk;
            for (;;) {
                pk = __hip_atomic_load(&g_chan[g][tid], __ATOMIC_RELAXED,
                                       __HIP_MEMORY_SCOPE_AGENT);
                if ((unsigned)(pk >> 32) == want) break;
                __builtin_amdgcn_s_sleep(1);
            }
            v_lds[tid] = __uint_as_float((unsigned)pk);
        }
        __syncthreads();   // v_lds ready; also separates g0's psum reuse

        // ---- steps loop: LDS-only body, NO global stores (critical path) ----
        float ureg[STEPS_PER_WG];   // u[t0+k][j], live in tid<128 only
        #pragma unroll
        for (int k = 0; k < STEPS_PER_WG; ++k) {
            float acc = 0.f;
            #pragma unroll
            for (int m = 0; m < 16; ++m)
                acc += v_lds[s * 16 + m] * w[k][m];   // LDS broadcast reads
            psum[s][j] = acc;
            __syncthreads();

            if (tid < 128) {
                float u = 0.f;
                #pragma unroll
                for (int ss = 0; ss < 8; ++ss) u += psum[ss][j];
                ureg[k] = u;
                const float vn = tanh_fast(ascal[k] * u);
                if (k < STEPS_PER_WG - 1) {
                    v_lds[j] = vn;
                } else if (g + 1 < N_CHAIN_WG) {
                    // Baton leaves HERE — everything after is shadow time.
                    const ull pk = (((ull)((gen << 8) | (unsigned)(g + 1))) << 32) |
                                   (ull)__float_as_uint(vn);
                    __hip_atomic_store(&g_chan[g + 1][j], pk, __ATOMIC_RELAXED,
                                       __HIP_MEMORY_SCOPE_AGENT);
                }
            }
            __syncthreads();   // protects psum reuse + v_lds update
        }

        // ---- post-baton publication (overlapped with next chain WG) ----
        if (tid < 128) {
            #pragma unroll
            for (int k = 0; k < STEPS_PER_WG; ++k) {
                const int t = t0 + k;
                const ull upk = (((ull)((gen << 8) | (unsigned)t)) << 32) |
                                (ull)__float_as_uint(ureg[k]);
                __hip_atomic_store(&g_uchan[t][j], upk, __ATOMIC_RELAXED,
                                   __HIP_MEMORY_SCOPE_AGENT);
            }
        }
        __syncthreads();   // every wave's uchan stores ACKed at LLC past here
        if (tid < STEPS_PER_WG) {
            const int t = t0 + tid;
            __hip_atomic_store(&g_uflag[t], (gen << 8) | (unsigned)t,
                               __ATOMIC_RELAXED, __HIP_MEMORY_SCOPE_AGENT);
        }
    } else {
        // ------------------------- writer role -----------------------------
        // Item i -> (t = i>>3, c = i&7): 128 output rows, 64 KB each.
        const int wid = bid - N_CHAIN_WG;
        const int j4  = tid & 31;                 // float4 column
        for (int i = wid; i < N_ITEMS; i += N_WRITER_WG) {
            const int t = i >> 3;
            const int c = i & 7;
            const unsigned want = (gen << 8) | (unsigned)t;
            if (tid == 0) {   // single poller per WG: LLC poll traffic ~KB/µs
                while (__hip_atomic_load(&g_uflag[t], __ATOMIC_RELAXED,
                                         __HIP_MEMORY_SCOPE_AGENT) != want)
                    __builtin_amdgcn_s_sleep(8);
            }
            __syncthreads();

            // One-shot u read from LLC (agent atomics — never the local L2).
            const ull e0 = __hip_atomic_load(&g_uchan[t][4 * j4 + 0], __ATOMIC_RELAXED, __HIP_MEMORY_SCOPE_AGENT);
            const ull e1 = __hip_atomic_load(&g_uchan[t][4 * j4 + 1], __ATOMIC_RELAXED, __HIP_MEMORY_SCOPE_AGENT);
            const ull e2 = __hip_atomic_load(&g_uchan[t][4 * j4 + 2], __ATOMIC_RELAXED, __HIP_MEMORY_SCOPE_AGENT);
            const ull e3 = __hip_atomic_load(&g_uchan[t][4 * j4 + 3], __ATOMIC_RELAXED, __HIP_MEMORY_SCOPE_AGENT);
            const float u0 = __uint_as_float((unsigned)e0);
            const float u1 = __uint_as_float((unsigned)e1);
            const float u2 = __uint_as_float((unsigned)e2);
            const float u3 = __uint_as_float((unsigned)e3);

            const int lbase = (c << 7) + (tid >> 5);
            #pragma unroll
            for (int p = 0; p < 4; ++p) {
                const int row = (t << 10) + lbase + (p << 5);   // t*1024 + l
                const float sc = a[row];
                floatx4 r;
                r.x = tanh_fast(sc * u0);
                r.y = tanh_fast(sc * u1);
                r.z = tanh_fast(sc * u2);
                r.w = tanh_fast(sc * u3);
                __builtin_nontemporal_store(r, (floatx4*)out + (((size_t)row) << 5) + j4);
            }
        }
    }

    // Generation bump: the 256th block to finish resets g_done and advances
    // g_gen. Every block read g_gen at entry (all resident from t=0), so no
    // block can observe the bump within this launch; the next launch (stream-
    // ordered) sees it via the kernel-boundary flush.
    __syncthreads();
    if (tid == 0) {
        const int old = atomicAdd(&g_done, 1);
        if (old == N_BLOCKS - 1) {
            __hip_atomic_store(&g_done, 0, __ATOMIC_RELAXED, __HIP_MEMORY_SCOPE_AGENT);
            __hip_atomic_store(&g_gen, gen + 1u, __ATOMIC_RELAXED, __HIP_MEMORY_SCOPE_AGENT);
        }
    }
}

// ---------------------------------------------------------------------------
extern "C" void kernel_launch(void* const* d_in, const int* in_sizes, int n_in,
                              void* d_out, int out_size, void* d_ws, size_t ws_size,
                              hipStream_t stream)
{
    const float* x        = (const float*)d_in[0];
    const float* pos_head = (const float*)d_in[1];
    const float* pos_tail = (const float*)d_in[2];
    const float* W        = (const float*)d_in[3];
    const float* a        = (const float*)d_in[4];
    float*       out      = (float*)d_out;

    hipLaunchKernelGGL(fused_kernel, dim3(N_BLOCKS), dim3(1024), 0, stream,
                       x, pos_head, pos_tail, W, a, out);
}